// Round 9
// baseline (502.731 us; speedup 1.0000x reference)
//
#include <hip/hip_runtime.h>
#include <hip/hip_bf16.h>
#include <math.h>

#define SEQ  2048
#define BATCH 8
#define NTOK (SEQ*BATCH)   // 16384 tokens

typedef __attribute__((ext_vector_type(8))) short short8v;
typedef __attribute__((ext_vector_type(4))) float f32x4;
typedef unsigned short u16;

__device__ __forceinline__ u16 f2bf(float f) {
    __hip_bfloat16 h = __float2bfloat16(f);
    return *reinterpret_cast<u16*>(&h);
}
__device__ __forceinline__ float bf2f(u16 u) {
    unsigned v = ((unsigned)u) << 16;
    return *reinterpret_cast<float*>(&v);
}
__device__ __forceinline__ unsigned pack_bf2(float a, float b) {
    __hip_bfloat162 h = __float22bfloat162_rn(float2{a, b});
    return *reinterpret_cast<unsigned*>(&h);
}
// async global->LDS, 16B per lane; LDS dest must be wave-uniform base + lane*16
__device__ __forceinline__ void gl_lds16(const u16* g, u16* l) {
    __builtin_amdgcn_global_load_lds(
        (const __attribute__((address_space(1))) unsigned int*)g,
        (__attribute__((address_space(3))) unsigned int*)l, 16, 0, 0);
}

// ---------------------------------------------------------------------------
// 0) weight convert + transpose:  W[K][N] fp32 -> Wt[N][K] bf16 (xscale).
//    Blocks 250..255: bias arena (qkv1 q-scaled, qkv2, dr2b, zero tail).
// ---------------------------------------------------------------------------
struct WDescs {
    const float* src[14];
    int K[14];
    int N[14];
    long dst[14];
    float scale[14];
    int tstart[15];
    const float* qb1; const float* kb1; const float* vb1;
    const float* qb2; const float* kb2; const float* vb2;
    const float* dr2b;
    float qs1, qs2;
};

__global__ __launch_bounds__(256) void convert_w_kernel(WDescs d, u16* __restrict__ WA,
                                                        float* __restrict__ BA) {
    int blk = blockIdx.x;
    int tid = threadIdx.x;
    if (blk >= 250) {                 // bias arena: 1280 floats over 5 blocks
        int t = (blk - 250) * 256 + tid;
        if      (t < 256)  BA[t] = d.qb1[t] * d.qs1;
        else if (t < 512)  BA[t] = d.kb1[t - 256];
        else if (t < 768)  BA[t] = d.vb1[t - 512];
        else if (t < 896)  BA[t] = d.qb2[t - 768] * d.qs2;
        else if (t < 1024) BA[t] = d.kb2[t - 896];
        else if (t < 1152) BA[t] = d.vb2[t - 1024];
        else if (t < 1216) BA[t] = d.dr2b[t - 1152];
        else if (t < 1280) BA[t] = 0.f;
        return;
    }
    __shared__ float tile[64][65];
    int di = 0;
    while (di < 13 && blk >= d.tstart[di + 1]) ++di;
    int t  = blk - d.tstart[di];
    int K  = d.K[di], N = d.N[di];
    int tn = N >> 6;
    int k0 = (t / tn) << 6, n0 = (t % tn) << 6;
    const float* src = d.src[di];
    float sc = d.scale[di];
    #pragma unroll
    for (int i = 0; i < 16; ++i) {
        int id = i * 256 + tid;
        int kk = id >> 6, nn = id & 63;
        tile[kk][nn] = src[(size_t)(k0 + kk) * N + n0 + nn];
    }
    __syncthreads();
    u16* dst = WA + d.dst[di];
    #pragma unroll
    for (int i = 0; i < 16; ++i) {
        int id = i * 256 + tid;
        int nn = id >> 6, kk = id & 63;
        dst[(size_t)(n0 + nn) * K + k0 + kk] = f2bf(tile[kk][nn] * sc);
    }
}

// ---------------------------------------------------------------------------
// 1) h = x + positional encoding (exp2/native trig)
// ---------------------------------------------------------------------------
__global__ __launch_bounds__(256) void add_pe_kernel(const float* __restrict__ x,
                                                     float* __restrict__ h,
                                                     u16* __restrict__ hb) {
    int idx = blockIdx.x * 256 + threadIdx.x;     // over SEQ*256
    int s = idx >> 8;
    int d = idx & 255;
    float inv = exp2f((float)d * -0.0519051264732f);
    float ang = (float)s * inv;
    float pe  = (d & 1) ? __cosf(ang) : __sinf(ang);
    #pragma unroll
    for (int b = 0; b < BATCH; ++b) {
        size_t g = ((size_t)(b * SEQ + s) << 8) + d;
        float v = x[g] + pe;
        h[g]  = v;
        hb[g] = f2bf(v);
    }
}

// ---------------------------------------------------------------------------
// 2) bf16 MFMA GEMM, T3 2-phase (round-8 structure, proven)
// ---------------------------------------------------------------------------
template<int BN, int RELU, int WF32, int WBF16, int MAXEP>
__global__ __launch_bounds__(256) void gemm_bf16_kernel(
    const u16* __restrict__ A, const u16* __restrict__ Bt,
    const float* __restrict__ bias, float* __restrict__ Cf,
    u16* __restrict__ Cb, float* __restrict__ Pm, int N, int K)
{
    constexpr int BM  = 64;
    constexpr int NMF = 2;
    constexpr int NBF = BN / 32;
    __shared__ u16 As[2][BM * 64];
    __shared__ u16 Bs[2][BN * 64];
    const int tid  = threadIdx.x;
    const int lane = tid & 63;
    const int c    = lane & 15, g = lane >> 4;
    const int w    = tid >> 6;
    const int wr   = w >> 1, wc = w & 1;
    const size_t bm = (size_t)blockIdx.y * BM;
    const size_t bn = (size_t)blockIdx.x * BN;

    f32x4 acc[NMF][NBF];
    #pragma unroll
    for (int i = 0; i < NMF; ++i)
        #pragma unroll
        for (int j = 0; j < NBF; ++j) acc[i][j] = (f32x4){0.f, 0.f, 0.f, 0.f};

    auto stage = [&](int buf, int t) {
        #pragma unroll
        for (int j = 0; j < BM / 32; ++j) {
            int cid = j * 256 + tid;
            int row = cid >> 3, blk = cid & 7;
            int sof = (blk ^ (row & 7)) * 8;
            gl_lds16(&A[(bm + row) * K + t * 64 + sof], &As[buf][cid * 8]);
        }
        #pragma unroll
        for (int j = 0; j < BN / 32; ++j) {
            int cid = j * 256 + tid;
            int row = cid >> 3, blk = cid & 7;
            int sof = (blk ^ (row & 7)) * 8;
            gl_lds16(&Bt[(bn + row) * K + t * 64 + sof], &Bs[buf][cid * 8]);
        }
    };

    const int nt = K >> 6;
    stage(0, 0);
    __syncthreads();
    for (int t = 0; t < nt; ++t) {
        if (t + 1 < nt) stage((t + 1) & 1, t + 1);
        const int bfi = t & 1;
        #pragma unroll
        for (int ks2 = 0; ks2 < 2; ++ks2) {
            short8v af[NMF], bfr[NBF];
            #pragma unroll
            for (int am = 0; am < NMF; ++am) {
                int r = wr * 32 + am * 16 + c;
                af[am] = *(const short8v*)&As[bfi][r * 64 + (((ks2 * 4 + g) ^ (r & 7)) * 8)];
            }
            #pragma unroll
            for (int bn_ = 0; bn_ < NBF; ++bn_) {
                int r = wc * (BN / 2) + bn_ * 16 + c;
                bfr[bn_] = *(const short8v*)&Bs[bfi][r * 64 + (((ks2 * 4 + g) ^ (r & 7)) * 8)];
            }
            #pragma unroll
            for (int am = 0; am < NMF; ++am)
                #pragma unroll
                for (int bn_ = 0; bn_ < NBF; ++bn_)
                    acc[am][bn_] = __builtin_amdgcn_mfma_f32_16x16x32_bf16(
                                       af[am], bfr[bn_], acc[am][bn_], 0, 0, 0);
        }
        __syncthreads();
    }

    float bv[NBF];
    #pragma unroll
    for (int bn_ = 0; bn_ < NBF; ++bn_) bv[bn_] = bias[bn + wc * (BN / 2) + bn_ * 16 + c];

    if (MAXEP) {
        __shared__ float cm[8][64];
        #pragma unroll
        for (int bn_ = 0; bn_ < NBF; ++bn_) {
            float lm = -INFINITY;
            #pragma unroll
            for (int am = 0; am < NMF; ++am)
                #pragma unroll
                for (int i = 0; i < 4; ++i)
                    lm = fmaxf(lm, acc[am][bn_][i] + bv[bn_]);
            cm[wr * 4 + g][wc * (BN / 2) + bn_ * 16 + c] = lm;
        }
        __syncthreads();
        if (tid < 64) {
            float m = cm[0][tid];
            #pragma unroll
            for (int k = 1; k < 8; ++k) m = fmaxf(m, cm[k][tid]);
            Pm[(size_t)blockIdx.y * 64 + tid] = m;
        }
        return;
    }

    #pragma unroll
    for (int am = 0; am < NMF; ++am) {
        #pragma unroll
        for (int bn_ = 0; bn_ < NBF; ++bn_) {
            #pragma unroll
            for (int i = 0; i < 4; ++i) {
                size_t row = bm + wr * 32 + am * 16 + 4 * g + i;
                size_t col = bn + wc * (BN / 2) + bn_ * 16 + c;
                float v = acc[am][bn_][i] + bv[bn_];
                if (RELU) v = fmaxf(v, 0.f);
                if (WF32)  Cf[row * N + col] = v;
                if (WBF16) Cb[row * N + col] = f2bf(v);
            }
        }
    }
}

// ---------------------------------------------------------------------------
// 3) LayerNorm(a + r) * g + b,  a: bf16, r: fp32
// ---------------------------------------------------------------------------
template<int D, int WRF>
__global__ __launch_bounds__(256) void ln_residual_kernel(
    const u16* __restrict__ a, const float* __restrict__ r,
    const float* __restrict__ g, const float* __restrict__ bb,
    float* __restrict__ out, u16* __restrict__ outb)
{
    const int N = D >> 6;
    int wave = threadIdx.x >> 6;
    int lane = threadIdx.x & 63;
    size_t token = (size_t)blockIdx.x * 4 + wave;
    const u16*   ar = a + token * D;
    const float* rr = r + token * D;

    float xv[N];
    float s = 0.f;
    #pragma unroll
    for (int i = 0; i < N; ++i) {
        int d = lane + (i << 6);
        xv[i] = bf2f(ar[d]) + rr[d];
        s += xv[i];
    }
    #pragma unroll
    for (int off = 1; off < 64; off <<= 1) s += __shfl_xor(s, off);
    float mean = s * (1.0f / D);
    float vs = 0.f;
    #pragma unroll
    for (int i = 0; i < N; ++i) { float d0 = xv[i] - mean; vs += d0 * d0; }
    #pragma unroll
    for (int off = 1; off < 64; off <<= 1) vs += __shfl_xor(vs, off);
    float inv = 1.0f / sqrtf(vs * (1.0f / D) + 1e-5f);
    #pragma unroll
    for (int i = 0; i < N; ++i) {
        int d = lane + (i << 6);
        float v = (xv[i] - mean) * inv * g[d] + bb[d];
        if (WRF) out[token * D + d] = v;
        outb[token * D + d] = f2bf(v);
    }
}

// ---------------------------------------------------------------------------
// 4) bf16-MFMA flash attention v5: 256 threads, 4 waves x 32 q-rows
//    (2 q-blocks/wave -> K/V fragments read once, used twice).
//    - V staged with key-pair b32 packed writes (keys k,k+16 adjacent in spos)
//    - Pb stride 72 u16 (rows spread over banks; writes 2-way = free)
//    - no setprio (r8 showed it regresses this barrier-synced kernel)
//    - p = exp2(s), no running max (q pre-scaled by log2e/sqrt(hd))
//    - XCD remap: all 16 q-blocks of one (b,h) share H%8
// ---------------------------------------------------------------------------
template<int HD>
__global__ __launch_bounds__(256) void flash_mfma_kernel(
    const u16* __restrict__ QKV, u16* __restrict__ Og, const u16* __restrict__ zsrc)
{
    constexpr int D    = 8 * HD;
    constexpr int SD   = 3 * D;
    constexpr int NDH  = HD / 16;
    constexpr int PSTR = 72;

    __shared__ u16 Ks[2][64 * 32];
    __shared__ u16 Vt[2][NDH * 16 * 64];
    __shared__ u16 Pb[128 * PSTR];

    const int tid  = threadIdx.x;
    const int w    = tid >> 6;
    const int lane = tid & 63;
    const int c    = lane & 15;
    const int g    = lane >> 4;

    const int H    = blockIdx.x + (blockIdx.y << 4);   // gridDim.x == 16
    const int bh   = H & 63;
    const int qblk = H >> 6;
    const int b = bh >> 3, hh = bh & 7;
    const size_t qvbase = (size_t)b * SEQ * SD + (size_t)hh * HD;
    const size_t obase  = (size_t)b * SEQ * D  + (size_t)hh * HD;
    const int qbase = qblk * 128;

    // ---- Q fragments (scale pre-folded into weights) ----
    short8v qf[2];
    #pragma unroll
    for (int qb = 0; qb < 2; ++qb) {
        if (HD == 16 && g >= 2) {
            short8v z = {0, 0, 0, 0, 0, 0, 0, 0};
            qf[qb] = z;
        } else {
            int qrow = qbase + w * 32 + qb * 16 + c;
            qf[qb] = *(const short8v*)&QKV[qvbase + (size_t)qrow * SD + 8 * g];
        }
    }

    f32x4 oacc[2][NDH];
    float lreg[2][4];
    #pragma unroll
    for (int qb = 0; qb < 2; ++qb) {
        #pragma unroll
        for (int dh = 0; dh < NDH; ++dh) oacc[qb][dh] = (f32x4){0.f, 0.f, 0.f, 0.f};
        #pragma unroll
        for (int i = 0; i < 4; ++i) lreg[qb][i] = 0.f;
    }

    // ---- staging roles ----
    // K: all 256 threads, one gl_lds each (row tid>>2, swizzled block)
    const int krow = tid >> 2;
    const int klb  = (tid & 3) ^ ((krow >> 1) & 3);
    const bool kzero = (HD == 16) && (klb >= 2);
    // V: threads 0..127, key-pair (k0, k0+16) x 8 channels, b32 packed writes
    const int kb    = tid >> 2;                        // 0..31 when tid<128
    const int k0    = (kb & 15) + 32 * (kb >> 4);      // {0..15, 32..47}
    const int sch   = (tid & 3) * 8;                   // 0,8,16,24
    const bool vstager = (tid < 128) && (HD == 32 || sch < 16);
    const int spos0 = 2 * (k0 & 15) + 32 * (k0 >> 5);  // partner is spos0+1
    const int squad = spos0 >> 3, soff = spos0 & 7;    // soff even
    const int vkc = (c & 7) ^ ((c & 8) >> 1);

    // ---- prologue: stage tile 0 into buf 0 ----
    gl_lds16(kzero ? zsrc : &QKV[qvbase + (size_t)krow * SD + D + klb * 8],
             &Ks[0][tid * 8]);
    if (vstager) {
        short8v va = *(const short8v*)&QKV[qvbase + (size_t)k0 * SD + 2 * D + sch];
        short8v vb = *(const short8v*)&QKV[qvbase + (size_t)(k0 + 16) * SD + 2 * D + sch];
        #pragma unroll
        for (int i = 0; i < 8; ++i) {
            int row = sch + i;
            int vk = (row & 7) ^ ((row & 8) >> 1);
            *(unsigned*)&Vt[0][row * 64 + ((squad ^ vk) << 3) + soff] =
                ((unsigned)(u16)va[i]) | (((unsigned)(u16)vb[i]) << 16);
        }
    }
    __syncthreads();

    const int NT = SEQ / 64;

    auto tile_body = [&](const int buf, const int t) {
        short8v vva = {0,0,0,0,0,0,0,0}, vvb = {0,0,0,0,0,0,0,0};
        const bool pre = (t + 1 < NT);
        if (pre) {   // issue next-tile loads early (T14)
            gl_lds16(kzero ? zsrc
                           : &QKV[qvbase + (size_t)((t + 1) * 64 + krow) * SD + D + klb * 8],
                     &Ks[buf ^ 1][tid * 8]);
            if (vstager) {
                const size_t nb = qvbase + (size_t)((t + 1) * 64) * SD + 2 * D + sch;
                vva = *(const short8v*)&QKV[nb + (size_t)k0 * SD];
                vvb = *(const short8v*)&QKV[nb + (size_t)(k0 + 16) * SD];
            }
        }

        // ---- shared fragments (used by both q-blocks) ----
        short8v kf[4];
        #pragma unroll
        for (int kh = 0; kh < 4; ++kh) {
            int row = 16 * kh + c;
            kf[kh] = *(const short8v*)&Ks[buf][row * 32 + ((g ^ ((c >> 1) & 3)) * 8)];
        }
        short8v vfr[NDH][2];
        #pragma unroll
        for (int dh = 0; dh < NDH; ++dh) {
            vfr[dh][0] = *(const short8v*)&Vt[buf][(16 * dh + c) * 64 + ((g ^ vkc) << 3)];
            vfr[dh][1] = *(const short8v*)&Vt[buf][(16 * dh + c) * 64 + (((4 + g) ^ vkc) << 3)];
        }

        #pragma unroll
        for (int qb = 0; qb < 2; ++qb) {
            // ---- QK^T ----
            f32x4 s[4];
            #pragma unroll
            for (int kh = 0; kh < 4; ++kh)
                s[kh] = __builtin_amdgcn_mfma_f32_16x16x32_bf16(
                            qf[qb], kf[kh], (f32x4){0.f, 0.f, 0.f, 0.f}, 0, 0, 0);

            // ---- softmax numerators + packed P write ----
            #pragma unroll
            for (int i = 0; i < 4; ++i) {
                float p0 = exp2f(s[0][i]);
                float p1 = exp2f(s[1][i]);
                float p2 = exp2f(s[2][i]);
                float p3 = exp2f(s[3][i]);
                lreg[qb][i] += (p0 + p1) + (p2 + p3);
                int rr = 4 * g + i;
                int pk = (rr & 7) ^ ((rr & 8) >> 1);
                int base = (w * 32 + qb * 16 + rr) * PSTR + 2 * (c & 3);
                *(unsigned*)&Pb[base + (((c >> 2) ^ pk) << 3)]       = pack_bf2(p0, p1);
                *(unsigned*)&Pb[base + ((((c >> 2) + 4) ^ pk) << 3)] = pack_bf2(p2, p3);
            }

            // ---- PV ----
            int prow = (w * 32 + qb * 16 + c) * PSTR;
            short8v pf0 = *(const short8v*)&Pb[prow + ((g ^ vkc) << 3)];
            short8v pf1 = *(const short8v*)&Pb[prow + (((4 + g) ^ vkc) << 3)];
            #pragma unroll
            for (int dh = 0; dh < NDH; ++dh) {
                oacc[qb][dh] = __builtin_amdgcn_mfma_f32_16x16x32_bf16(pf0, vfr[dh][0], oacc[qb][dh], 0, 0, 0);
                oacc[qb][dh] = __builtin_amdgcn_mfma_f32_16x16x32_bf16(pf1, vfr[dh][1], oacc[qb][dh], 0, 0, 0);
            }
        }

        // late half of T14: packed V writes after compute
        if (pre && vstager) {
            #pragma unroll
            for (int i = 0; i < 8; ++i) {
                int row = sch + i;
                int vk = (row & 7) ^ ((row & 8) >> 1);
                *(unsigned*)&Vt[buf ^ 1][row * 64 + ((squad ^ vk) << 3) + soff] =
                    ((unsigned)(u16)vva[i]) | (((unsigned)(u16)vvb[i]) << 16);
            }
        }
        __syncthreads();
    };

    for (int t = 0; t < NT; t += 2) {     // literal buf -> static LDS addressing
        tile_body(0, t);
        tile_body(1, t + 1);
    }

    // ---- epilogue: O = acc / l ----
    #pragma unroll
    for (int qb = 0; qb < 2; ++qb) {
        #pragma unroll
        for (int i = 0; i < 4; ++i) {
            float li = lreg[qb][i];
            li += __shfl_xor(li, 1);
            li += __shfl_xor(li, 2);
            li += __shfl_xor(li, 4);
            li += __shfl_xor(li, 8);
            float inv = 1.0f / li;
            int qrow = qbase + w * 32 + qb * 16 + 4 * g + i;
            #pragma unroll
            for (int dh = 0; dh < NDH; ++dh)
                Og[obase + (size_t)qrow * D + 16 * dh + c] = f2bf(oacc[qb][dh][i] * inv);
        }
    }
}

// ---------------------------------------------------------------------------
// 5) head: pool partials [256][64] -> pooled[8][64] -> w3 -> w4 -> out[8][14]
// ---------------------------------------------------------------------------
__global__ __launch_bounds__(256) void head_kernel(
    const float* __restrict__ Pm,
    const float* __restrict__ w3, const float* __restrict__ b3,
    const float* __restrict__ w4, const float* __restrict__ b4,
    float* __restrict__ out)
{
    __shared__ float pooled[8][64];
    __shared__ float t2[8][32];
    int tid = threadIdx.x;
    #pragma unroll
    for (int rep = 0; rep < 2; ++rep) {
        int idx = rep * 256 + tid;            // 0..511
        int b = idx >> 6, d = idx & 63;
        float m = -INFINITY;
        #pragma unroll
        for (int k = 0; k < 32; ++k)
            m = fmaxf(m, Pm[(size_t)(b * 32 + k) * 64 + d]);
        pooled[b][d] = m;
    }
    __syncthreads();
    {
        int b = tid >> 5, j = tid & 31;
        float s = b3[j];
        #pragma unroll
        for (int k = 0; k < 64; ++k) s = fmaf(pooled[b][k], w3[k * 32 + j], s);
        t2[b][j] = s;
    }
    __syncthreads();
    if (tid < 8 * 14) {
        int b = tid / 14, j = tid % 14;
        float s = b4[j];
        #pragma unroll
        for (int k = 0; k < 32; ++k) s = fmaf(t2[b][k], w4[k * 14 + j], s);
        out[b * 14 + j] = s;
    }
}

// ---------------------------------------------------------------------------
extern "C" void kernel_launch(void* const* d_in, const int* in_sizes, int n_in,
                              void* d_out, int out_size, void* d_ws, size_t ws_size,
                              hipStream_t stream) {
    const float* x     = (const float*)d_in[0];
    const float* qw1   = (const float*)d_in[1];
    const float* qb1   = (const float*)d_in[2];
    const float* kw1   = (const float*)d_in[3];
    const float* kb1   = (const float*)d_in[4];
    const float* vw1   = (const float*)d_in[5];
    const float* vb1   = (const float*)d_in[6];
    const float* ow1   = (const float*)d_in[7];
    const float* ob1   = (const float*)d_in[8];
    const float* f1w1  = (const float*)d_in[9];
    const float* f1b1  = (const float*)d_in[10];
    const float* f2w1  = (const float*)d_in[11];
    const float* f2b1  = (const float*)d_in[12];
    const float* ln1g1 = (const float*)d_in[13];
    const float* ln1b1 = (const float*)d_in[14];
    const float* ln2g1 = (const float*)d_in[15];
    const float* ln2b1 = (const float*)d_in[16];
    const float* qw2   = (const float*)d_in[17];
    const float* qb2   = (const float*)d_in[18];
    const float* kw2   = (const float*)d_in[19];
    const float* kb2   = (const float*)d_in[20];
    const float* vw2   = (const float*)d_in[21];
    const float* vb2   = (const float*)d_in[22];
    const float* ow2   = (const float*)d_in[23];
    const float* ob2   = (const float*)d_in[24];
    const float* f1w2  = (const float*)d_in[25];
    const float* f1b2  = (const float*)d_in[26];
    const float* f2w2  = (const float*)d_in[27];
    const float* f2b2  = (const float*)d_in[28];
    const float* ln1g2 = (const float*)d_in[29];
    const float* ln1b2 = (const float*)d_in[30];
    const float* ln2g2 = (const float*)d_in[31];
    const float* ln2b2 = (const float*)d_in[32];
    const float* dr1w  = (const float*)d_in[33];
    const float* dr1b  = (const float*)d_in[34];
    const float* dr2w  = (const float*)d_in[35];
    const float* dr2b  = (const float*)d_in[36];
    const float* dr3w  = (const float*)d_in[37];
    const float* dr3b  = (const float*)d_in[38];
    const float* dr4w  = (const float*)d_in[39];
    const float* dr4b  = (const float*)d_in[40];

    const size_t T = NTOK;
    float* F1 = (float*)d_ws;            // [T,256] fp32 residual enc1 / Pmax at the end
    float* F2 = F1 + T * 256;            // [T,256] fp32 residual enc2
    u16*   E1 = (u16*)(F2 + T * 256);    // [T,256] bf16
    u16*   E2 = E1 + T * 256;            // [T,256] bf16
    u16*   E3 = E2 + T * 256;            // [T,256] bf16
    u16*   Dq = E3 + T * 256;            // [T,1024] bf16 (qkv-packed / ff scratch)
    u16*   WA = Dq + T * 1024;           // bf16 weight arena
    float* BA = (float*)(WA + 1048576);  // bias arena (1280 floats; tail 64 = zeros)
    const u16* ZS = (const u16*)(BA + 1216);   // 256B of zeros (flash K padding)

    const float QS1 = 0.25503488f;       // log2e / sqrt(32)
    const float QS2 = 0.36067376f;       // log2e / sqrt(16)

    WDescs wd;
    const float* srcs[14] = {qw1, kw1, vw1, ow1, f1w1, f2w1, dr1w,
                             qw2, kw2, vw2, ow2, f1w2, f2w2, dr2w};
    int Ks_[14]  = {256, 256, 256, 256, 256, 1024, 256, 128, 128, 128, 128, 128, 512, 128};
    int Ns_[14]  = {256, 256, 256, 256, 1024, 256, 128, 128, 128, 128, 128, 512, 128, 64};
    long dsts[14] = {0, 65536, 131072, 196608, 262144, 524288, 786432,
                     819200, 835584, 851968, 868352, 884736, 950272, 1015808};
    float scs[14] = {QS1, 1.f, 1.f, 1.f, 1.f, 1.f, 1.f, QS2, 1.f, 1.f, 1.f, 1.f, 1.f, 1.f};
    int tst[15] = {0, 16, 32, 48, 64, 128, 192, 200, 204, 208, 212, 216, 232, 248, 250};
    for (int i = 0; i < 14; ++i) {
        wd.src[i] = srcs[i]; wd.K[i] = Ks_[i]; wd.N[i] = Ns_[i];
        wd.dst[i] = dsts[i]; wd.scale[i] = scs[i];
    }
    for (int i = 0; i < 15; ++i) wd.tstart[i] = tst[i];
    wd.qb1 = qb1; wd.kb1 = kb1; wd.vb1 = vb1;
    wd.qb2 = qb2; wd.kb2 = kb2; wd.vb2 = vb2;
    wd.dr2b = dr2b; wd.qs1 = QS1; wd.qs2 = QS2;

    const dim3 blk(256);

    convert_w_kernel<<<256, blk, 0, stream>>>(wd, WA, BA);

    add_pe_kernel<<<SEQ, blk, 0, stream>>>(x, F1, E1);

    // ================= encoder 1 (d=256, ff=1024, hd=32) =================
    gemm_bf16_kernel<128,0,0,1,0><<<dim3(6, 256), blk, 0, stream>>>(E1, WA + 0,      BA,   nullptr, Dq, nullptr, 768, 256);
    flash_mfma_kernel<32><<<dim3(16, 64), blk, 0, stream>>>(Dq, E2, ZS);
    gemm_bf16_kernel< 64,0,0,1,0><<<dim3(4, 256), blk, 0, stream>>>(E2, WA + 196608, ob1,  nullptr, E3, nullptr, 256, 256);
    ln_residual_kernel<256,1><<<NTOK / 4, blk, 0, stream>>>(E3, F1, ln1g1, ln1b1, F1, E1);
    gemm_bf16_kernel<128,1,0,1,0><<<dim3(8, 256), blk, 0, stream>>>(E1, WA + 262144, f1b1, nullptr, Dq, nullptr, 1024, 256);
    gemm_bf16_kernel< 64,0,0,1,0><<<dim3(4, 256), blk, 0, stream>>>(Dq, WA + 524288, f2b1, nullptr, E3, nullptr, 256, 1024);
    ln_residual_kernel<256,1><<<NTOK / 4, blk, 0, stream>>>(E3, F1, ln2g1, ln2b1, F1, E1);

    // ---- 256 -> 128 (fp32 residual base for enc2 + bf16 GEMM input) ----
    gemm_bf16_kernel< 64,0,1,1,0><<<dim3(2, 256), blk, 0, stream>>>(E1, WA + 786432, dr1b, F2, E2, nullptr, 128, 256);

    // ================= encoder 2 (d=128, ff=512, hd=16) =================
    gemm_bf16_kernel<128,0,0,1,0><<<dim3(3, 256), blk, 0, stream>>>(E2, WA + 819200, BA + 768, nullptr, Dq, nullptr, 384, 128);
    flash_mfma_kernel<16><<<dim3(16, 64), blk, 0, stream>>>(Dq, E3, ZS);
    gemm_bf16_kernel< 64,0,0,1,0><<<dim3(2, 256), blk, 0, stream>>>(E3, WA + 868352, ob2,  nullptr, E2, nullptr, 128, 128);
    ln_residual_kernel<128,1><<<NTOK / 4, blk, 0, stream>>>(E2, F2, ln1g2, ln1b2, F2, E1);
    gemm_bf16_kernel<128,1,0,1,0><<<dim3(4, 256), blk, 0, stream>>>(E1, WA + 884736, f1b2, nullptr, Dq, nullptr, 512, 128);
    gemm_bf16_kernel< 64,0,0,1,0><<<dim3(2, 256), blk, 0, stream>>>(Dq, WA + 950272, f2b2, nullptr, E2, nullptr, 128, 512);
    ln_residual_kernel<128,0><<<NTOK / 4, blk, 0, stream>>>(E2, F2, ln2g2, ln2b2, nullptr, E1);

    // ---- 128 -> 64 with fused column-max epilogue -> Pmax [256][64] in F1 ----
    gemm_bf16_kernel< 64,0,0,0,1><<<dim3(1, 256), blk, 0, stream>>>(E1, WA + 1015808, BA + 1152, nullptr, nullptr, F1, 64, 128);
    head_kernel<<<1, blk, 0, stream>>>(F1, dr3w, dr3b, dr4w, dr4b, (float*)d_out);
}

// Round 10
// 483.751 us; speedup vs baseline: 1.0392x; 1.0392x over previous
//
#include <hip/hip_runtime.h>
#include <hip/hip_bf16.h>
#include <math.h>

#define SEQ  2048
#define BATCH 8
#define NTOK (SEQ*BATCH)   // 16384 tokens

typedef __attribute__((ext_vector_type(8))) short short8v;
typedef __attribute__((ext_vector_type(4))) float f32x4;
typedef unsigned short u16;

__device__ __forceinline__ u16 f2bf(float f) {
    __hip_bfloat16 h = __float2bfloat16(f);
    return *reinterpret_cast<u16*>(&h);
}
__device__ __forceinline__ float bf2f(u16 u) {
    unsigned v = ((unsigned)u) << 16;
    return *reinterpret_cast<float*>(&v);
}
__device__ __forceinline__ unsigned pack_bf2(float a, float b) {
    __hip_bfloat162 h = __float22bfloat162_rn(float2{a, b});
    return *reinterpret_cast<unsigned*>(&h);
}
// async global->LDS, 16B per lane; LDS dest must be wave-uniform base + lane*16
__device__ __forceinline__ void gl_lds16(const u16* g, u16* l) {
    __builtin_amdgcn_global_load_lds(
        (const __attribute__((address_space(1))) unsigned int*)g,
        (__attribute__((address_space(3))) unsigned int*)l, 16, 0, 0);
}

// ---------------------------------------------------------------------------
// 0) weight convert + transpose:  W[K][N] fp32 -> Wt[N][K] bf16 (xscale).
//    Blocks 250..255: bias arena (qkv1 q-scaled, qkv2, dr2b, zero tail).
// ---------------------------------------------------------------------------
struct WDescs {
    const float* src[14];
    int K[14];
    int N[14];
    long dst[14];
    float scale[14];
    int tstart[15];
    const float* qb1; const float* kb1; const float* vb1;
    const float* qb2; const float* kb2; const float* vb2;
    const float* dr2b;
    float qs1, qs2;
};

__global__ __launch_bounds__(256) void convert_w_kernel(WDescs d, u16* __restrict__ WA,
                                                        float* __restrict__ BA) {
    int blk = blockIdx.x;
    int tid = threadIdx.x;
    if (blk >= 250) {                 // bias arena: 1280 floats over 5 blocks
        int t = (blk - 250) * 256 + tid;
        if      (t < 256)  BA[t] = d.qb1[t] * d.qs1;
        else if (t < 512)  BA[t] = d.kb1[t - 256];
        else if (t < 768)  BA[t] = d.vb1[t - 512];
        else if (t < 896)  BA[t] = d.qb2[t - 768] * d.qs2;
        else if (t < 1024) BA[t] = d.kb2[t - 896];
        else if (t < 1152) BA[t] = d.vb2[t - 1024];
        else if (t < 1216) BA[t] = d.dr2b[t - 1152];
        else if (t < 1280) BA[t] = 0.f;
        return;
    }
    __shared__ float tile[64][65];
    int di = 0;
    while (di < 13 && blk >= d.tstart[di + 1]) ++di;
    int t  = blk - d.tstart[di];
    int K  = d.K[di], N = d.N[di];
    int tn = N >> 6;
    int k0 = (t / tn) << 6, n0 = (t % tn) << 6;
    const float* src = d.src[di];
    float sc = d.scale[di];
    #pragma unroll
    for (int i = 0; i < 16; ++i) {
        int id = i * 256 + tid;
        int kk = id >> 6, nn = id & 63;
        tile[kk][nn] = src[(size_t)(k0 + kk) * N + n0 + nn];
    }
    __syncthreads();
    u16* dst = WA + d.dst[di];
    #pragma unroll
    for (int i = 0; i < 16; ++i) {
        int id = i * 256 + tid;
        int nn = id >> 6, kk = id & 63;
        dst[(size_t)(n0 + nn) * K + k0 + kk] = f2bf(tile[kk][nn] * sc);
    }
}

// ---------------------------------------------------------------------------
// 1) h = x + positional encoding (exp2/native trig)
// ---------------------------------------------------------------------------
__global__ __launch_bounds__(256) void add_pe_kernel(const float* __restrict__ x,
                                                     float* __restrict__ h,
                                                     u16* __restrict__ hb) {
    int idx = blockIdx.x * 256 + threadIdx.x;     // over SEQ*256
    int s = idx >> 8;
    int d = idx & 255;
    float inv = exp2f((float)d * -0.0519051264732f);
    float ang = (float)s * inv;
    float pe  = (d & 1) ? __cosf(ang) : __sinf(ang);
    #pragma unroll
    for (int b = 0; b < BATCH; ++b) {
        size_t g = ((size_t)(b * SEQ + s) << 8) + d;
        float v = x[g] + pe;
        h[g]  = v;
        hb[g] = f2bf(v);
    }
}

// ---------------------------------------------------------------------------
// 2) bf16 MFMA GEMM, T3 2-phase (round-8 structure, proven)
// ---------------------------------------------------------------------------
template<int BN, int RELU, int WF32, int WBF16, int MAXEP>
__global__ __launch_bounds__(256) void gemm_bf16_kernel(
    const u16* __restrict__ A, const u16* __restrict__ Bt,
    const float* __restrict__ bias, float* __restrict__ Cf,
    u16* __restrict__ Cb, float* __restrict__ Pm, int N, int K)
{
    constexpr int BM  = 64;
    constexpr int NMF = 2;
    constexpr int NBF = BN / 32;
    __shared__ u16 As[2][BM * 64];
    __shared__ u16 Bs[2][BN * 64];
    const int tid  = threadIdx.x;
    const int lane = tid & 63;
    const int c    = lane & 15, g = lane >> 4;
    const int w    = tid >> 6;
    const int wr   = w >> 1, wc = w & 1;
    const size_t bm = (size_t)blockIdx.y * BM;
    const size_t bn = (size_t)blockIdx.x * BN;

    f32x4 acc[NMF][NBF];
    #pragma unroll
    for (int i = 0; i < NMF; ++i)
        #pragma unroll
        for (int j = 0; j < NBF; ++j) acc[i][j] = (f32x4){0.f, 0.f, 0.f, 0.f};

    auto stage = [&](int buf, int t) {
        #pragma unroll
        for (int j = 0; j < BM / 32; ++j) {
            int cid = j * 256 + tid;
            int row = cid >> 3, blk = cid & 7;
            int sof = (blk ^ (row & 7)) * 8;
            gl_lds16(&A[(bm + row) * K + t * 64 + sof], &As[buf][cid * 8]);
        }
        #pragma unroll
        for (int j = 0; j < BN / 32; ++j) {
            int cid = j * 256 + tid;
            int row = cid >> 3, blk = cid & 7;
            int sof = (blk ^ (row & 7)) * 8;
            gl_lds16(&Bt[(bn + row) * K + t * 64 + sof], &Bs[buf][cid * 8]);
        }
    };

    const int nt = K >> 6;
    stage(0, 0);
    __syncthreads();
    for (int t = 0; t < nt; ++t) {
        if (t + 1 < nt) stage((t + 1) & 1, t + 1);
        const int bfi = t & 1;
        #pragma unroll
        for (int ks2 = 0; ks2 < 2; ++ks2) {
            short8v af[NMF], bfr[NBF];
            #pragma unroll
            for (int am = 0; am < NMF; ++am) {
                int r = wr * 32 + am * 16 + c;
                af[am] = *(const short8v*)&As[bfi][r * 64 + (((ks2 * 4 + g) ^ (r & 7)) * 8)];
            }
            #pragma unroll
            for (int bn_ = 0; bn_ < NBF; ++bn_) {
                int r = wc * (BN / 2) + bn_ * 16 + c;
                bfr[bn_] = *(const short8v*)&Bs[bfi][r * 64 + (((ks2 * 4 + g) ^ (r & 7)) * 8)];
            }
            #pragma unroll
            for (int am = 0; am < NMF; ++am)
                #pragma unroll
                for (int bn_ = 0; bn_ < NBF; ++bn_)
                    acc[am][bn_] = __builtin_amdgcn_mfma_f32_16x16x32_bf16(
                                       af[am], bfr[bn_], acc[am][bn_], 0, 0, 0);
        }
        __syncthreads();
    }

    float bv[NBF];
    #pragma unroll
    for (int bn_ = 0; bn_ < NBF; ++bn_) bv[bn_] = bias[bn + wc * (BN / 2) + bn_ * 16 + c];

    if (MAXEP) {
        __shared__ float cm[8][64];
        #pragma unroll
        for (int bn_ = 0; bn_ < NBF; ++bn_) {
            float lm = -INFINITY;
            #pragma unroll
            for (int am = 0; am < NMF; ++am)
                #pragma unroll
                for (int i = 0; i < 4; ++i)
                    lm = fmaxf(lm, acc[am][bn_][i] + bv[bn_]);
            cm[wr * 4 + g][wc * (BN / 2) + bn_ * 16 + c] = lm;
        }
        __syncthreads();
        if (tid < 64) {
            float m = cm[0][tid];
            #pragma unroll
            for (int k = 1; k < 8; ++k) m = fmaxf(m, cm[k][tid]);
            Pm[(size_t)blockIdx.y * 64 + tid] = m;
        }
        return;
    }

    #pragma unroll
    for (int am = 0; am < NMF; ++am) {
        #pragma unroll
        for (int bn_ = 0; bn_ < NBF; ++bn_) {
            #pragma unroll
            for (int i = 0; i < 4; ++i) {
                size_t row = bm + wr * 32 + am * 16 + 4 * g + i;
                size_t col = bn + wc * (BN / 2) + bn_ * 16 + c;
                float v = acc[am][bn_][i] + bv[bn_];
                if (RELU) v = fmaxf(v, 0.f);
                if (WF32)  Cf[row * N + col] = v;
                if (WBF16) Cb[row * N + col] = f2bf(v);
            }
        }
    }
}

// ---------------------------------------------------------------------------
// 3) LayerNorm(a + r) * g + b,  a: bf16, r: fp32
// ---------------------------------------------------------------------------
template<int D, int WRF>
__global__ __launch_bounds__(256) void ln_residual_kernel(
    const u16* __restrict__ a, const float* __restrict__ r,
    const float* __restrict__ g, const float* __restrict__ bb,
    float* __restrict__ out, u16* __restrict__ outb)
{
    const int N = D >> 6;
    int wave = threadIdx.x >> 6;
    int lane = threadIdx.x & 63;
    size_t token = (size_t)blockIdx.x * 4 + wave;
    const u16*   ar = a + token * D;
    const float* rr = r + token * D;

    float xv[N];
    float s = 0.f;
    #pragma unroll
    for (int i = 0; i < N; ++i) {
        int d = lane + (i << 6);
        xv[i] = bf2f(ar[d]) + rr[d];
        s += xv[i];
    }
    #pragma unroll
    for (int off = 1; off < 64; off <<= 1) s += __shfl_xor(s, off);
    float mean = s * (1.0f / D);
    float vs = 0.f;
    #pragma unroll
    for (int i = 0; i < N; ++i) { float d0 = xv[i] - mean; vs += d0 * d0; }
    #pragma unroll
    for (int off = 1; off < 64; off <<= 1) vs += __shfl_xor(vs, off);
    float inv = 1.0f / sqrtf(vs * (1.0f / D) + 1e-5f);
    #pragma unroll
    for (int i = 0; i < N; ++i) {
        int d = lane + (i << 6);
        float v = (xv[i] - mean) * inv * g[d] + bb[d];
        if (WRF) out[token * D + d] = v;
        outb[token * D + d] = f2bf(v);
    }
}

// ---------------------------------------------------------------------------
// 4) bf16-MFMA flash attention (round-7 v4, the measured-best variant):
//    512 threads, 8 waves x 16 q-rows, K-loop unrolled x2 with literal
//    buffer indices, waves 0-3 stage K via gl_lds / waves 4-7 reg-stage V
//    (T14 split), Ks block-XOR swizzle, Vt/Pb vk swizzle, p = exp2(s),
//    XCD remap.  NO setprio (regressed in round 8).
// ---------------------------------------------------------------------------
template<int HD>
__global__ __launch_bounds__(512) void flash_mfma_kernel(
    const u16* __restrict__ QKV, u16* __restrict__ Og, const u16* __restrict__ zsrc)
{
    constexpr int D   = 8 * HD;
    constexpr int SD  = 3 * D;
    constexpr int NDH = HD / 16;

    __shared__ u16 Ks[2][64 * 32];
    __shared__ u16 Vt[2][NDH * 16 * 64];
    __shared__ u16 Pb[128 * 64];

    const int tid  = threadIdx.x;
    const int w    = tid >> 6;
    const int lane = tid & 63;
    const int c    = lane & 15;
    const int g    = lane >> 4;

    const int H    = blockIdx.x + (blockIdx.y << 4);   // gridDim.x == 16
    const int bh   = H & 63;
    const int qblk = H >> 6;
    const int b = bh >> 3, hh = bh & 7;
    const size_t qvbase = (size_t)b * SEQ * SD + (size_t)hh * HD;
    const size_t obase  = (size_t)b * SEQ * D  + (size_t)hh * HD;
    const int qbase = qblk * 128;

    // ---- Q fragment (scale pre-folded into weights) ----
    short8v qf;
    if (HD == 16 && g >= 2) {
        short8v z = {0, 0, 0, 0, 0, 0, 0, 0};
        qf = z;
    } else {
        int qrow = qbase + w * 16 + c;
        qf = *(const short8v*)&QKV[qvbase + (size_t)qrow * SD + 8 * g];
    }

    f32x4 oacc[NDH];
    float lreg[4];
    #pragma unroll
    for (int dh = 0; dh < NDH; ++dh) oacc[dh] = (f32x4){0.f, 0.f, 0.f, 0.f};
    #pragma unroll
    for (int i = 0; i < 4; ++i) lreg[i] = 0.f;

    // ---- staging roles ----
    const bool kstager = (tid < 256);
    const int krow = tid >> 2;                     // 0..63 (valid when kstager)
    const int klb  = (tid & 3) ^ ((krow >> 1) & 3);
    const bool kzero = (HD == 16) && (klb >= 2);

    const int vtid = tid - 256;
    const int skey = vtid >> 2;                    // 0..63
    const int sch  = (vtid & 3) * 8;               // 0,8,16,24
    const bool vstager = (tid >= 256) && (HD == 32 || sch < 16);
    const int spos  = ((skey >> 5) << 5) + 2 * (skey & 15) + ((skey >> 4) & 1);
    const int squad = spos >> 3, soff = spos & 7;
    const int vkc = (c & 7) ^ ((c & 8) >> 1);

    // ---- prologue: stage tile 0 into buf 0 ----
    if (kstager)
        gl_lds16(kzero ? zsrc : &QKV[qvbase + (size_t)krow * SD + D + klb * 8],
                 &Ks[0][tid * 8]);
    if (vstager) {
        short8v v0 = *(const short8v*)&QKV[qvbase + (size_t)skey * SD + 2 * D + sch];
        #pragma unroll
        for (int i = 0; i < 8; ++i) {
            int row = sch + i;
            int vk = (row & 7) ^ ((row & 8) >> 1);
            Vt[0][row * 64 + ((squad ^ vk) << 3) + soff] = (u16)v0[i];
        }
    }
    __syncthreads();

    const int NT = SEQ / 64;

    auto tile_body = [&](const int buf, const int t) {
        short8v vv = {0, 0, 0, 0, 0, 0, 0, 0};
        const bool pre = (t + 1 < NT);
        if (pre) {   // issue next-tile loads early (T14)
            if (kstager)
                gl_lds16(kzero ? zsrc
                               : &QKV[qvbase + (size_t)((t + 1) * 64 + krow) * SD + D + klb * 8],
                         &Ks[buf ^ 1][tid * 8]);
            if (vstager)
                vv = *(const short8v*)&QKV[qvbase + (size_t)((t + 1) * 64 + skey) * SD + 2 * D + sch];
        }

        // ---- fragments ----
        short8v kf[4];
        #pragma unroll
        for (int kh = 0; kh < 4; ++kh) {
            int row = 16 * kh + c;
            kf[kh] = *(const short8v*)&Ks[buf][row * 32 + ((g ^ ((c >> 1) & 3)) * 8)];
        }
        short8v vfr[NDH][2];
        #pragma unroll
        for (int dh = 0; dh < NDH; ++dh) {
            vfr[dh][0] = *(const short8v*)&Vt[buf][(16 * dh + c) * 64 + ((g ^ vkc) << 3)];
            vfr[dh][1] = *(const short8v*)&Vt[buf][(16 * dh + c) * 64 + (((4 + g) ^ vkc) << 3)];
        }

        // ---- QK^T ----
        f32x4 s[4];
        #pragma unroll
        for (int kh = 0; kh < 4; ++kh)
            s[kh] = __builtin_amdgcn_mfma_f32_16x16x32_bf16(
                        qf, kf[kh], (f32x4){0.f, 0.f, 0.f, 0.f}, 0, 0, 0);

        // ---- softmax numerators + packed P write ----
        #pragma unroll
        for (int i = 0; i < 4; ++i) {
            float p0 = exp2f(s[0][i]);
            float p1 = exp2f(s[1][i]);
            float p2 = exp2f(s[2][i]);
            float p3 = exp2f(s[3][i]);
            lreg[i] += (p0 + p1) + (p2 + p3);
            int rr = 4 * g + i;
            int pk = (rr & 7) ^ ((rr & 8) >> 1);
            int base = (w * 16 + rr) * 64 + 2 * (c & 3);
            *(unsigned*)&Pb[base + (((c >> 2) ^ pk) << 3)]       = pack_bf2(p0, p1);
            *(unsigned*)&Pb[base + ((((c >> 2) + 4) ^ pk) << 3)] = pack_bf2(p2, p3);
        }

        // ---- PV ----
        short8v pf0 = *(const short8v*)&Pb[(w * 16 + c) * 64 + ((g ^ vkc) << 3)];
        short8v pf1 = *(const short8v*)&Pb[(w * 16 + c) * 64 + (((4 + g) ^ vkc) << 3)];
        #pragma unroll
        for (int dh = 0; dh < NDH; ++dh) {
            oacc[dh] = __builtin_amdgcn_mfma_f32_16x16x32_bf16(pf0, vfr[dh][0], oacc[dh], 0, 0, 0);
            oacc[dh] = __builtin_amdgcn_mfma_f32_16x16x32_bf16(pf1, vfr[dh][1], oacc[dh], 0, 0, 0);
        }

        // late half of T14: V scatter write after compute
        if (pre && vstager) {
            #pragma unroll
            for (int i = 0; i < 8; ++i) {
                int row = sch + i;
                int vk = (row & 7) ^ ((row & 8) >> 1);
                Vt[buf ^ 1][row * 64 + ((squad ^ vk) << 3) + soff] = (u16)vv[i];
            }
        }
        __syncthreads();
    };

    for (int t = 0; t < NT; t += 2) {     // unroll x2: literal buf -> static LDS addrs
        tile_body(0, t);
        tile_body(1, t + 1);
    }

    // ---- epilogue: O = acc / l ----
    #pragma unroll
    for (int i = 0; i < 4; ++i) {
        float li = lreg[i];
        li += __shfl_xor(li, 1);
        li += __shfl_xor(li, 2);
        li += __shfl_xor(li, 4);
        li += __shfl_xor(li, 8);
        float inv = 1.0f / li;
        int qrow = qbase + w * 16 + 4 * g + i;
        #pragma unroll
        for (int dh = 0; dh < NDH; ++dh)
            Og[obase + (size_t)qrow * D + 16 * dh + c] = f2bf(oacc[dh][i] * inv);
    }
}

// ---------------------------------------------------------------------------
// 5) head: pool partials [256][64] -> pooled[8][64] -> w3 -> w4 -> out[8][14]
// ---------------------------------------------------------------------------
__global__ __launch_bounds__(256) void head_kernel(
    const float* __restrict__ Pm,
    const float* __restrict__ w3, const float* __restrict__ b3,
    const float* __restrict__ w4, const float* __restrict__ b4,
    float* __restrict__ out)
{
    __shared__ float pooled[8][64];
    __shared__ float t2[8][32];
    int tid = threadIdx.x;
    #pragma unroll
    for (int rep = 0; rep < 2; ++rep) {
        int idx = rep * 256 + tid;            // 0..511
        int b = idx >> 6, d = idx & 63;
        float m = -INFINITY;
        #pragma unroll
        for (int k = 0; k < 32; ++k)
            m = fmaxf(m, Pm[(size_t)(b * 32 + k) * 64 + d]);
        pooled[b][d] = m;
    }
    __syncthreads();
    {
        int b = tid >> 5, j = tid & 31;
        float s = b3[j];
        #pragma unroll
        for (int k = 0; k < 64; ++k) s = fmaf(pooled[b][k], w3[k * 32 + j], s);
        t2[b][j] = s;
    }
    __syncthreads();
    if (tid < 8 * 14) {
        int b = tid / 14, j = tid % 14;
        float s = b4[j];
        #pragma unroll
        for (int k = 0; k < 32; ++k) s = fmaf(t2[b][k], w4[k * 14 + j], s);
        out[b * 14 + j] = s;
    }
}

// ---------------------------------------------------------------------------
extern "C" void kernel_launch(void* const* d_in, const int* in_sizes, int n_in,
                              void* d_out, int out_size, void* d_ws, size_t ws_size,
                              hipStream_t stream) {
    const float* x     = (const float*)d_in[0];
    const float* qw1   = (const float*)d_in[1];
    const float* qb1   = (const float*)d_in[2];
    const float* kw1   = (const float*)d_in[3];
    const float* kb1   = (const float*)d_in[4];
    const float* vw1   = (const float*)d_in[5];
    const float* vb1   = (const float*)d_in[6];
    const float* ow1   = (const float*)d_in[7];
    const float* ob1   = (const float*)d_in[8];
    const float* f1w1  = (const float*)d_in[9];
    const float* f1b1  = (const float*)d_in[10];
    const float* f2w1  = (const float*)d_in[11];
    const float* f2b1  = (const float*)d_in[12];
    const float* ln1g1 = (const float*)d_in[13];
    const float* ln1b1 = (const float*)d_in[14];
    const float* ln2g1 = (const float*)d_in[15];
    const float* ln2b1 = (const float*)d_in[16];
    const float* qw2   = (const float*)d_in[17];
    const float* qb2   = (const float*)d_in[18];
    const float* kw2   = (const float*)d_in[19];
    const float* kb2   = (const float*)d_in[20];
    const float* vw2   = (const float*)d_in[21];
    const float* vb2   = (const float*)d_in[22];
    const float* ow2   = (const float*)d_in[23];
    const float* ob2   = (const float*)d_in[24];
    const float* f1w2  = (const float*)d_in[25];
    const float* f1b2  = (const float*)d_in[26];
    const float* f2w2  = (const float*)d_in[27];
    const float* f2b2  = (const float*)d_in[28];
    const float* ln1g2 = (const float*)d_in[29];
    const float* ln1b2 = (const float*)d_in[30];
    const float* ln2g2 = (const float*)d_in[31];
    const float* ln2b2 = (const float*)d_in[32];
    const float* dr1w  = (const float*)d_in[33];
    const float* dr1b  = (const float*)d_in[34];
    const float* dr2w  = (const float*)d_in[35];
    const float* dr2b  = (const float*)d_in[36];
    const float* dr3w  = (const float*)d_in[37];
    const float* dr3b  = (const float*)d_in[38];
    const float* dr4w  = (const float*)d_in[39];
    const float* dr4b  = (const float*)d_in[40];

    const size_t T = NTOK;
    float* F1 = (float*)d_ws;            // [T,256] fp32 residual enc1 / Pmax at the end
    float* F2 = F1 + T * 256;            // [T,256] fp32 residual enc2
    u16*   E1 = (u16*)(F2 + T * 256);    // [T,256] bf16
    u16*   E2 = E1 + T * 256;            // [T,256] bf16
    u16*   E3 = E2 + T * 256;            // [T,256] bf16
    u16*   Dq = E3 + T * 256;            // [T,1024] bf16 (qkv-packed / ff scratch)
    u16*   WA = Dq + T * 1024;           // bf16 weight arena
    float* BA = (float*)(WA + 1048576);  // bias arena (1280 floats; tail 64 = zeros)
    const u16* ZS = (const u16*)(BA + 1216);   // 256B of zeros (flash K padding)

    const float QS1 = 0.25503488f;       // log2e / sqrt(32)
    const float QS2 = 0.36067376f;       // log2e / sqrt(16)

    WDescs wd;
    const float* srcs[14] = {qw1, kw1, vw1, ow1, f1w1, f2w1, dr1w,
                             qw2, kw2, vw2, ow2, f1w2, f2w2, dr2w};
    int Ks_[14]  = {256, 256, 256, 256, 256, 1024, 256, 128, 128, 128, 128, 128, 512, 128};
    int Ns_[14]  = {256, 256, 256, 256, 1024, 256, 128, 128, 128, 128, 128, 512, 128, 64};
    long dsts[14] = {0, 65536, 131072, 196608, 262144, 524288, 786432,
                     819200, 835584, 851968, 868352, 884736, 950272, 1015808};
    float scs[14] = {QS1, 1.f, 1.f, 1.f, 1.f, 1.f, 1.f, QS2, 1.f, 1.f, 1.f, 1.f, 1.f, 1.f};
    int tst[15] = {0, 16, 32, 48, 64, 128, 192, 200, 204, 208, 212, 216, 232, 248, 250};
    for (int i = 0; i < 14; ++i) {
        wd.src[i] = srcs[i]; wd.K[i] = Ks_[i]; wd.N[i] = Ns_[i];
        wd.dst[i] = dsts[i]; wd.scale[i] = scs[i];
    }
    for (int i = 0; i < 15; ++i) wd.tstart[i] = tst[i];
    wd.qb1 = qb1; wd.kb1 = kb1; wd.vb1 = vb1;
    wd.qb2 = qb2; wd.kb2 = kb2; wd.vb2 = vb2;
    wd.dr2b = dr2b; wd.qs1 = QS1; wd.qs2 = QS2;

    const dim3 blk(256);
    const dim3 blk512(512);

    convert_w_kernel<<<256, blk, 0, stream>>>(wd, WA, BA);

    add_pe_kernel<<<SEQ, blk, 0, stream>>>(x, F1, E1);

    // ================= encoder 1 (d=256, ff=1024, hd=32) =================
    gemm_bf16_kernel<128,0,0,1,0><<<dim3(6, 256), blk, 0, stream>>>(E1, WA + 0,      BA,   nullptr, Dq, nullptr, 768, 256);
    flash_mfma_kernel<32><<<dim3(16, 64), blk512, 0, stream>>>(Dq, E2, ZS);
    gemm_bf16_kernel< 64,0,0,1,0><<<dim3(4, 256), blk, 0, stream>>>(E2, WA + 196608, ob1,  nullptr, E3, nullptr, 256, 256);
    ln_residual_kernel<256,1><<<NTOK / 4, blk, 0, stream>>>(E3, F1, ln1g1, ln1b1, F1, E1);
    gemm_bf16_kernel<128,1,0,1,0><<<dim3(8, 256), blk, 0, stream>>>(E1, WA + 262144, f1b1, nullptr, Dq, nullptr, 1024, 256);
    gemm_bf16_kernel< 64,0,0,1,0><<<dim3(4, 256), blk, 0, stream>>>(Dq, WA + 524288, f2b1, nullptr, E3, nullptr, 256, 1024);
    ln_residual_kernel<256,1><<<NTOK / 4, blk, 0, stream>>>(E3, F1, ln2g1, ln2b1, F1, E1);

    // ---- 256 -> 128 (fp32 residual base for enc2 + bf16 GEMM input) ----
    gemm_bf16_kernel< 64,0,1,1,0><<<dim3(2, 256), blk, 0, stream>>>(E1, WA + 786432, dr1b, F2, E2, nullptr, 128, 256);

    // ================= encoder 2 (d=128, ff=512, hd=16) =================
    gemm_bf16_kernel<128,0,0,1,0><<<dim3(3, 256), blk, 0, stream>>>(E2, WA + 819200, BA + 768, nullptr, Dq, nullptr, 384, 128);
    flash_mfma_kernel<16><<<dim3(16, 64), blk512, 0, stream>>>(Dq, E3, ZS);
    gemm_bf16_kernel< 64,0,0,1,0><<<dim3(2, 256), blk, 0, stream>>>(E3, WA + 868352, ob2,  nullptr, E2, nullptr, 128, 128);
    ln_residual_kernel<128,1><<<NTOK / 4, blk, 0, stream>>>(E2, F2, ln1g2, ln1b2, F2, E1);
    gemm_bf16_kernel<128,1,0,1,0><<<dim3(4, 256), blk, 0, stream>>>(E1, WA + 884736, f1b2, nullptr, Dq, nullptr, 512, 128);
    gemm_bf16_kernel< 64,0,0,1,0><<<dim3(2, 256), blk, 0, stream>>>(Dq, WA + 950272, f2b2, nullptr, E2, nullptr, 128, 512);
    ln_residual_kernel<128,0><<<NTOK / 4, blk, 0, stream>>>(E2, F2, ln2g2, ln2b2, nullptr, E1);

    // ---- 128 -> 64 with fused column-max epilogue -> Pmax [256][64] in F1 ----
    gemm_bf16_kernel< 64,0,0,0,1><<<dim3(1, 256), blk, 0, stream>>>(E1, WA + 1015808, BA + 1152, nullptr, nullptr, F1, 64, 128);
    head_kernel<<<1, blk, 0, stream>>>(F1, dr3w, dr3b, dr4w, dr4b, (float*)d_out);
}